// Round 5
// baseline (525.753 us; speedup 1.0000x reference)
//
#include <hip/hip_runtime.h>

#define NN 50000
#define FEAT 128
#define DBINS 256

// Detect whether edge_index is stored as int64 (high 32-bit words all zero).
// Also zeroes the degree-bin histogram (piggyback to save a dispatch).
__global__ void detect_idx_kernel(const unsigned int* ei32, int* flag, int* degbins) {
    __shared__ int ok;
    if (threadIdx.x == 0) ok = 1;
    degbins[threadIdx.x] = 0;
    __syncthreads();
    if (ei32[2 * threadIdx.x + 1] != 0u) ok = 0;   // benign race: all writers write 0
    __syncthreads();
    if (threadIdx.x == 0) *flag = ok;
}

static __device__ __forceinline__ void load_edge(const void* ei, int is64, int E, int e,
                                                 int& src, int& dst) {
    if (is64) {
        const long long* p = (const long long*)ei;
        src = (int)p[e];
        dst = (int)p[E + e];
    } else {
        const int* p = (const int*)ei;
        src = p[e];
        dst = p[E + e];
    }
}

// ---------------- CSR build ----------------
__global__ void hist_kernel(const void* ei, const int* flag, int* hist, int E) {
    int e = blockIdx.x * blockDim.x + threadIdx.x;
    if (e >= E) return;
    int src, dst;
    load_edge(ei, *flag, E, e, src, dst);
    atomicAdd(&hist[dst], 1);
}

// phase 1: per-block (256) scan -> local excl offsets + block sums + dinv + degree-bin hist
__global__ void scan_local_kernel(const int* __restrict__ hist, int* __restrict__ local_excl,
                                  int* __restrict__ bsum, float* __restrict__ dinv,
                                  int* __restrict__ degbins, int n) {
    __shared__ int sdata[256];
    int i = blockIdx.x * 256 + threadIdx.x;
    int v = (i < n) ? hist[i] : 0;
    if (i < n) {
        dinv[i] = (v > 0) ? rsqrtf((float)v) : 0.0f;
        atomicAdd(&degbins[v < (DBINS - 1) ? v : (DBINS - 1)], 1);
    }
    sdata[threadIdx.x] = v;
    __syncthreads();
    for (int d = 1; d < 256; d <<= 1) {
        int t = (threadIdx.x >= (unsigned)d) ? sdata[threadIdx.x - d] : 0;
        __syncthreads();
        sdata[threadIdx.x] += t;
        __syncthreads();
    }
    if (i < n) local_excl[i] = sdata[threadIdx.x] - v;
    if (threadIdx.x == 255) bsum[blockIdx.x] = sdata[255];
}

// phase 2: single-block exclusive scan of block sums (nb <= 1024)
__global__ void scan_bsum_kernel(int* bsum, int nb) {
    __shared__ int sdata[1024];
    int v = ((int)threadIdx.x < nb) ? bsum[threadIdx.x] : 0;
    sdata[threadIdx.x] = v;
    __syncthreads();
    for (int d = 1; d < 1024; d <<= 1) {
        int t = (threadIdx.x >= (unsigned)d) ? sdata[threadIdx.x - d] : 0;
        __syncthreads();
        sdata[threadIdx.x] += t;
        __syncthreads();
    }
    if ((int)threadIdx.x < nb) bsum[threadIdx.x] = sdata[threadIdx.x] - v;
}

// phase 3: add block offsets -> row_ptr + cursor; thread 0 writes row_ptr[n]=E
__global__ void scan_add_kernel(const int* __restrict__ local_excl, const int* __restrict__ bsum,
                                int* __restrict__ rowp, int* __restrict__ curs, int n, int E) {
    int i = blockIdx.x * 256 + threadIdx.x;
    if (i < n) {
        int r = local_excl[i] + bsum[i >> 8];
        rowp[i] = r;
        curs[i] = r;
    }
    if (i == 0) rowp[n] = E;
}

// exclusive scan of the 256 degree bins -> bin cursors (in place)
__global__ void degbin_scan_kernel(int* degbins) {
    __shared__ int sdata[DBINS];
    int v = degbins[threadIdx.x];
    sdata[threadIdx.x] = v;
    __syncthreads();
    for (int d = 1; d < DBINS; d <<= 1) {
        int t = (threadIdx.x >= (unsigned)d) ? sdata[threadIdx.x - d] : 0;
        __syncthreads();
        sdata[threadIdx.x] += t;
        __syncthreads();
    }
    degbins[threadIdx.x] = sdata[threadIdx.x] - v;
}

// counting-sort scatter: perm[] = node ids ordered by degree
__global__ void perm_scatter_kernel(const int* __restrict__ hist, int* __restrict__ degbins,
                                    int* __restrict__ perm, int n) {
    int i = blockIdx.x * 256 + threadIdx.x;
    if (i >= n) return;
    int d = hist[i];
    d = d < (DBINS - 1) ? d : (DBINS - 1);
    int pos = atomicAdd(&degbins[d], 1);
    perm[pos] = i;
}

// scatter {src, weight} as one int2
__global__ void scatter_kernel(const void* ei, const int* flag, int* cursor,
                               int2* __restrict__ edge,
                               const float* __restrict__ dinv, int E) {
    int e = blockIdx.x * blockDim.x + threadIdx.x;
    if (e >= E) return;
    int src, dst;
    load_edge(ei, *flag, E, e, src, dst);
    int pos = atomicAdd(&cursor[dst], 1);
    float w = dinv[src] * dinv[dst];
    edge[pos] = make_int2(src, __float_as_int(w));
}

static __device__ __forceinline__ float4 relu4(float4 v) {
    v.x = fmaxf(v.x, 0.0f); v.y = fmaxf(v.y, 0.0f);
    v.z = fmaxf(v.z, 0.0f); v.w = fmaxf(v.w, 0.0f);
    return v;
}

static __device__ __forceinline__ void fma4(float4& a, float w, float4 v) {
    a.x += w * v.x; a.y += w * v.y; a.z += w * v.z; a.w += w * v.w;
}

// ---------------- CSR conv: 32 threads/node (degree-sorted), float4/thread,
// padded predicated 4-way ILP loop (no serial tail) ----------------
template <bool RELU_IN, bool RELU_OUT>
__global__ void conv_csr_kernel(const float* __restrict__ xin,
                                const int* __restrict__ row_ptr,
                                const int2* __restrict__ edge,
                                const int* __restrict__ perm,
                                float* __restrict__ out) {
    int gid = blockIdx.x * blockDim.x + threadIdx.x;
    int snode = gid >> 5;
    int f4    = gid & 31;
    if (snode >= NN) return;
    int node = perm[snode];
    int beg = row_ptr[node];
    int end = row_ptr[node + 1];
    const float4* xv = (const float4*)xin;

    float4 a0 = make_float4(0.f, 0.f, 0.f, 0.f);
    float4 a1 = a0, a2 = a0, a3 = a0;

    int iters = (end - beg + 3) >> 2;
    int last = end - 1;
    for (int it = 0; it < iters; ++it) {
        int base = beg + (it << 2);
        int i0 = base + 0, i1 = base + 1, i2 = base + 2, i3 = base + 3;
        int2 e0 = edge[i0 < end ? i0 : last];
        int2 e1 = edge[i1 < end ? i1 : last];
        int2 e2 = edge[i2 < end ? i2 : last];
        int2 e3 = edge[i3 < end ? i3 : last];
        float w0 = (i0 < end) ? __int_as_float(e0.y) : 0.0f;
        float w1 = (i1 < end) ? __int_as_float(e1.y) : 0.0f;
        float w2 = (i2 < end) ? __int_as_float(e2.y) : 0.0f;
        float w3 = (i3 < end) ? __int_as_float(e3.y) : 0.0f;
        float4 v0 = xv[e0.x * 32 + f4];
        float4 v1 = xv[e1.x * 32 + f4];
        float4 v2 = xv[e2.x * 32 + f4];
        float4 v3 = xv[e3.x * 32 + f4];
        if (RELU_IN) { v0 = relu4(v0); v1 = relu4(v1); v2 = relu4(v2); v3 = relu4(v3); }
        fma4(a0, w0, v0);
        fma4(a1, w1, v1);
        fma4(a2, w2, v2);
        fma4(a3, w3, v3);
    }

    float4 acc;
    acc.x = (a0.x + a1.x) + (a2.x + a3.x);
    acc.y = (a0.y + a1.y) + (a2.y + a3.y);
    acc.z = (a0.z + a1.z) + (a2.z + a3.z);
    acc.w = (a0.w + a1.w) + (a2.w + a3.w);
    if (RELU_OUT) acc = relu4(acc);
    ((float4*)out)[node * 32 + f4] = acc;
}

// ---------------- fallback (atomic) path kernels ----------------
__global__ void deg_kernel(const void* ei, const int* flag, float* deg, int E) {
    int e = blockIdx.x * blockDim.x + threadIdx.x;
    if (e >= E) return;
    int src, dst;
    load_edge(ei, *flag, E, e, src, dst);
    atomicAdd(&deg[dst], 1.0f);
}

__global__ void dinv_kernel(float* deg) {
    int i = blockIdx.x * blockDim.x + threadIdx.x;
    if (i >= NN) return;
    float d = deg[i];
    deg[i] = (d > 0.0f) ? (1.0f / sqrtf(d)) : 0.0f;
}

template <bool RELU_IN>
__global__ void conv_atomic_kernel(const float* __restrict__ xin, const void* ei, const int* flag,
                                   const float* __restrict__ dinv, float* __restrict__ yout, int E) {
    int gid = blockIdx.x * blockDim.x + threadIdx.x;
    int e  = gid >> 5;
    int f4 = gid & 31;
    if (e >= E) return;
    int src, dst;
    load_edge(ei, *flag, E, e, src, dst);
    float w = dinv[src] * dinv[dst];
    float4 v = ((const float4*)xin)[src * 32 + f4];
    if (RELU_IN) v = relu4(v);
    float* o = yout + (size_t)dst * FEAT + f4 * 4;
    atomicAdd(o + 0, v.x * w);
    atomicAdd(o + 1, v.y * w);
    atomicAdd(o + 2, v.z * w);
    atomicAdd(o + 3, v.w * w);
}

__global__ void relu_kernel(float4* buf, int n4) {
    int i = blockIdx.x * blockDim.x + threadIdx.x;
    if (i >= n4) return;
    buf[i] = relu4(buf[i]);
}

extern "C" void kernel_launch(void* const* d_in, const int* in_sizes, int n_in,
                              void* d_out, int out_size, void* d_ws, size_t ws_size,
                              hipStream_t stream) {
    const float* x  = (const float*)d_in[0];
    const void*  ei = d_in[1];
    const int E = in_sizes[1] / 2;

    float* out = (float*)d_out;
    char*  ws  = (char*)d_ws;

    const size_t feat_bytes = (size_t)NN * FEAT * sizeof(float);
    const int NB = (NN + 255) / 256;

    // ws layout (CSR path)
    const size_t OFF_FLAG = 0;
    const size_t OFF_DBIN = 1024;
    const size_t OFF_HIST = OFF_DBIN + ((DBINS * 4 + 255) & ~255ull);
    const size_t OFF_DINV = OFF_HIST + (((size_t)NN * 4 + 255) & ~255ull);
    const size_t OFF_ROWP = OFF_DINV + (((size_t)NN * 4 + 255) & ~255ull);
    const size_t OFF_CURS = OFF_ROWP + ((((size_t)NN + 1) * 4 + 255) & ~255ull);
    const size_t OFF_BSUM = OFF_CURS + (((size_t)NN * 4 + 255) & ~255ull);
    const size_t OFF_PERM = OFF_BSUM + ((1024 * 4 + 255) & ~255ull);
    const size_t OFF_EDG  = OFF_PERM + (((size_t)NN * 4 + 255) & ~255ull);
    const size_t OFF_Y    = OFF_EDG + (((size_t)E * 8 + 255) & ~255ull);
    const size_t NEEDED   = OFF_Y + feat_bytes;

    int* flag = (int*)(ws + OFF_FLAG);

    if (ws_size >= NEEDED) {
        int*   dbin = (int*)(ws + OFF_DBIN);
        int*   hist = (int*)(ws + OFF_HIST);
        float* dinv = (float*)(ws + OFF_DINV);
        int*   rowp = (int*)(ws + OFF_ROWP);
        int*   curs = (int*)(ws + OFF_CURS);
        int*   bsum = (int*)(ws + OFF_BSUM);
        int*   perm = (int*)(ws + OFF_PERM);
        int2*  edge = (int2*)(ws + OFF_EDG);
        float* y    = (float*)(ws + OFF_Y);

        hipMemsetAsync(hist, 0, NN * sizeof(int), stream);
        detect_idx_kernel<<<1, 256, 0, stream>>>((const unsigned int*)ei, flag, dbin);

        hist_kernel<<<(E + 255) / 256, 256, 0, stream>>>(ei, flag, hist, E);
        scan_local_kernel<<<NB, 256, 0, stream>>>(hist, rowp, bsum, dinv, dbin, NN);
        scan_bsum_kernel<<<1, 1024, 0, stream>>>(bsum, NB);
        scan_add_kernel<<<NB, 256, 0, stream>>>(rowp, bsum, rowp, curs, NN, E);
        degbin_scan_kernel<<<1, DBINS, 0, stream>>>(dbin);
        perm_scatter_kernel<<<NB, 256, 0, stream>>>(hist, dbin, perm, NN);
        scatter_kernel<<<(E + 255) / 256, 256, 0, stream>>>(ei, flag, curs, edge, dinv, E);

        const int conv_blocks = (NN * 32 + 255) / 256;
        // layer 1: x -> out
        conv_csr_kernel<false, false><<<conv_blocks, 256, 0, stream>>>(x, rowp, edge, perm, out);
        // layer 2: relu(out) -> y
        conv_csr_kernel<true, false><<<conv_blocks, 256, 0, stream>>>(out, rowp, edge, perm, y);
        // layer 3: relu(y) -> out (+ final relu fused)
        conv_csr_kernel<true, true><<<conv_blocks, 256, 0, stream>>>(y, rowp, edge, perm, out);
    } else {
        // fallback: atomic implementation
        float* dinv = (float*)(ws + 1024);
        float* y    = (float*)(ws + 262144);

        hipMemsetAsync(dinv, 0, NN * sizeof(float), stream);
        hipMemsetAsync(out, 0, feat_bytes, stream);
        hipMemsetAsync(y, 0, feat_bytes, stream);

        detect_idx_kernel<<<1, 256, 0, stream>>>((const unsigned int*)ei, flag, (int*)(ws + 512));
        deg_kernel<<<(E + 255) / 256, 256, 0, stream>>>(ei, flag, dinv, E);
        dinv_kernel<<<(NN + 255) / 256, 256, 0, stream>>>(dinv);

        const int conv_blocks = (int)(((size_t)E * 32 + 255) / 256);
        conv_atomic_kernel<false><<<conv_blocks, 256, 0, stream>>>(x, ei, flag, dinv, out, E);
        conv_atomic_kernel<true><<<conv_blocks, 256, 0, stream>>>(out, ei, flag, dinv, y, E);
        hipMemsetAsync(out, 0, feat_bytes, stream);
        conv_atomic_kernel<true><<<conv_blocks, 256, 0, stream>>>(y, ei, flag, dinv, out, E);
        relu_kernel<<<(out_size / 4 + 255) / 256, 256, 0, stream>>>((float4*)out, out_size / 4);
    }
}

// Round 6
// 206.402 us; speedup vs baseline: 2.5472x; 2.5472x over previous
//
#include <hip/hip_runtime.h>

#define NN 50000
#define FEAT 128

// Detect whether edge_index is stored as int64 (high 32-bit words all zero)
__global__ void detect_idx_kernel(const unsigned int* ei32, int* flag) {
    __shared__ int ok;
    if (threadIdx.x == 0) ok = 1;
    __syncthreads();
    if (ei32[2 * threadIdx.x + 1] != 0u) ok = 0;   // benign race: all writers write 0
    __syncthreads();
    if (threadIdx.x == 0) *flag = ok;
}

static __device__ __forceinline__ void load_edge(const void* ei, int is64, int E, int e,
                                                 int& src, int& dst) {
    if (is64) {
        const long long* p = (const long long*)ei;
        src = (int)p[e];
        dst = (int)p[E + e];
    } else {
        const int* p = (const int*)ei;
        src = p[e];
        dst = p[E + e];
    }
}

// ---------------- CSR build ----------------
__global__ void hist_kernel(const void* ei, const int* flag, int* hist, int E) {
    int e = blockIdx.x * blockDim.x + threadIdx.x;
    if (e >= E) return;
    int src, dst;
    load_edge(ei, *flag, E, e, src, dst);
    atomicAdd(&hist[dst], 1);
}

// phase 1: per-block (256) scan -> local excl offsets + block sums + dinv (fused)
__global__ void scan_local_kernel(const int* __restrict__ hist, int* __restrict__ local_excl,
                                  int* __restrict__ bsum, float* __restrict__ dinv, int n) {
    __shared__ int sdata[256];
    int i = blockIdx.x * 256 + threadIdx.x;
    int v = (i < n) ? hist[i] : 0;
    if (i < n) dinv[i] = (v > 0) ? rsqrtf((float)v) : 0.0f;
    sdata[threadIdx.x] = v;
    __syncthreads();
    for (int d = 1; d < 256; d <<= 1) {
        int t = (threadIdx.x >= (unsigned)d) ? sdata[threadIdx.x - d] : 0;
        __syncthreads();
        sdata[threadIdx.x] += t;
        __syncthreads();
    }
    if (i < n) local_excl[i] = sdata[threadIdx.x] - v;
    if (threadIdx.x == 255) bsum[blockIdx.x] = sdata[255];
}

// phase 2: single-block exclusive scan of block sums (nb <= 1024)
__global__ void scan_bsum_kernel(int* bsum, int nb) {
    __shared__ int sdata[1024];
    int v = ((int)threadIdx.x < nb) ? bsum[threadIdx.x] : 0;
    sdata[threadIdx.x] = v;
    __syncthreads();
    for (int d = 1; d < 1024; d <<= 1) {
        int t = (threadIdx.x >= (unsigned)d) ? sdata[threadIdx.x - d] : 0;
        __syncthreads();
        sdata[threadIdx.x] += t;
        __syncthreads();
    }
    if ((int)threadIdx.x < nb) bsum[threadIdx.x] = sdata[threadIdx.x] - v;
}

// phase 3: add block offsets -> row_ptr + cursor; thread 0 writes row_ptr[n]=E
__global__ void scan_add_kernel(const int* __restrict__ local_excl, const int* __restrict__ bsum,
                                int* __restrict__ rowp, int* __restrict__ curs, int n, int E) {
    int i = blockIdx.x * 256 + threadIdx.x;
    if (i < n) {
        int r = local_excl[i] + bsum[i >> 8];
        rowp[i] = r;
        curs[i] = r;
    }
    if (i == 0) rowp[n] = E;
}

// scatter {src, weight} packed into one 8-byte word (low 32 = src, high 32 = w bits)
__global__ void scatter_kernel(const void* ei, const int* flag, int* cursor,
                               unsigned long long* __restrict__ edge,
                               const float* __restrict__ dinv, int E) {
    int e = blockIdx.x * blockDim.x + threadIdx.x;
    if (e >= E) return;
    int src, dst;
    load_edge(ei, *flag, E, e, src, dst);
    int pos = atomicAdd(&cursor[dst], 1);
    float w = dinv[src] * dinv[dst];
    edge[pos] = (unsigned long long)(unsigned int)src |
                ((unsigned long long)(unsigned int)__float_as_int(w) << 32);
}

static __device__ __forceinline__ float4 relu4(float4 v) {
    v.x = fmaxf(v.x, 0.0f); v.y = fmaxf(v.y, 0.0f);
    v.z = fmaxf(v.z, 0.0f); v.w = fmaxf(v.w, 0.0f);
    return v;
}

static __device__ __forceinline__ void fma4(float4& a, float w, float4 v) {
    a.x += w * v.x; a.y += w * v.y; a.z += w * v.z; a.w += w * v.w;
}

// ---------------- CSR conv ----------------
// 32 threads/node, float4/thread. Per 32-edge chunk: ONE coalesced packed-edge
// load (lane i holds edge i), then shfl-broadcast + 8-way-ILP clamped gathers.
template <bool RELU_IN, bool RELU_OUT>
__global__ void conv_csr_kernel(const float* __restrict__ xin,
                                const int* __restrict__ row_ptr,
                                const unsigned long long* __restrict__ edge,
                                float* __restrict__ out) {
    int gid = blockIdx.x * blockDim.x + threadIdx.x;
    int node = gid >> 5;
    int f4   = gid & 31;
    if (node >= NN) return;
    int beg = row_ptr[node];
    int end = row_ptr[node + 1];
    const float4* xv = (const float4*)xin;

    float4 a0 = make_float4(0.f, 0.f, 0.f, 0.f);
    float4 a1 = a0, a2 = a0, a3 = a0;

    for (int cb = beg; cb < end; cb += 32) {
        int rem = end - cb;               // > 0
        int myi = (f4 < rem) ? f4 : 0;
        unsigned long long pk = edge[cb + myi];   // one coalesced 8B load / lane

        for (int j = 0; j < rem; j += 8) {
            int i0 = j + 0, i1 = j + 1, i2 = j + 2, i3 = j + 3;
            int i4 = j + 4, i5 = j + 5, i6 = j + 6, i7 = j + 7;
            int last = rem - 1;
            unsigned long long l0 = __shfl(pk, i0 < rem ? i0 : last, 32);
            unsigned long long l1 = __shfl(pk, i1 < rem ? i1 : last, 32);
            unsigned long long l2 = __shfl(pk, i2 < rem ? i2 : last, 32);
            unsigned long long l3 = __shfl(pk, i3 < rem ? i3 : last, 32);
            unsigned long long l4 = __shfl(pk, i4 < rem ? i4 : last, 32);
            unsigned long long l5 = __shfl(pk, i5 < rem ? i5 : last, 32);
            unsigned long long l6 = __shfl(pk, i6 < rem ? i6 : last, 32);
            unsigned long long l7 = __shfl(pk, i7 < rem ? i7 : last, 32);

            float w0 = (i0 < rem) ? __int_as_float((int)(l0 >> 32)) : 0.0f;
            float w1 = (i1 < rem) ? __int_as_float((int)(l1 >> 32)) : 0.0f;
            float w2 = (i2 < rem) ? __int_as_float((int)(l2 >> 32)) : 0.0f;
            float w3 = (i3 < rem) ? __int_as_float((int)(l3 >> 32)) : 0.0f;
            float w4 = (i4 < rem) ? __int_as_float((int)(l4 >> 32)) : 0.0f;
            float w5 = (i5 < rem) ? __int_as_float((int)(l5 >> 32)) : 0.0f;
            float w6 = (i6 < rem) ? __int_as_float((int)(l6 >> 32)) : 0.0f;
            float w7 = (i7 < rem) ? __int_as_float((int)(l7 >> 32)) : 0.0f;

            float4 v0 = xv[(int)(unsigned int)l0 * 32 + f4];
            float4 v1 = xv[(int)(unsigned int)l1 * 32 + f4];
            float4 v2 = xv[(int)(unsigned int)l2 * 32 + f4];
            float4 v3 = xv[(int)(unsigned int)l3 * 32 + f4];
            float4 v4 = xv[(int)(unsigned int)l4 * 32 + f4];
            float4 v5 = xv[(int)(unsigned int)l5 * 32 + f4];
            float4 v6 = xv[(int)(unsigned int)l6 * 32 + f4];
            float4 v7 = xv[(int)(unsigned int)l7 * 32 + f4];

            if (RELU_IN) {
                v0 = relu4(v0); v1 = relu4(v1); v2 = relu4(v2); v3 = relu4(v3);
                v4 = relu4(v4); v5 = relu4(v5); v6 = relu4(v6); v7 = relu4(v7);
            }
            fma4(a0, w0, v0);
            fma4(a1, w1, v1);
            fma4(a2, w2, v2);
            fma4(a3, w3, v3);
            fma4(a0, w4, v4);
            fma4(a1, w5, v5);
            fma4(a2, w6, v6);
            fma4(a3, w7, v7);
        }
    }

    float4 acc;
    acc.x = (a0.x + a1.x) + (a2.x + a3.x);
    acc.y = (a0.y + a1.y) + (a2.y + a3.y);
    acc.z = (a0.z + a1.z) + (a2.z + a3.z);
    acc.w = (a0.w + a1.w) + (a2.w + a3.w);
    if (RELU_OUT) acc = relu4(acc);
    ((float4*)out)[node * 32 + f4] = acc;
}

// ---------------- fallback (atomic) path kernels ----------------
__global__ void deg_kernel(const void* ei, const int* flag, float* deg, int E) {
    int e = blockIdx.x * blockDim.x + threadIdx.x;
    if (e >= E) return;
    int src, dst;
    load_edge(ei, *flag, E, e, src, dst);
    atomicAdd(&deg[dst], 1.0f);
}

__global__ void dinv_kernel(float* deg) {
    int i = blockIdx.x * blockDim.x + threadIdx.x;
    if (i >= NN) return;
    float d = deg[i];
    deg[i] = (d > 0.0f) ? (1.0f / sqrtf(d)) : 0.0f;
}

template <bool RELU_IN>
__global__ void conv_atomic_kernel(const float* __restrict__ xin, const void* ei, const int* flag,
                                   const float* __restrict__ dinv, float* __restrict__ yout, int E) {
    int gid = blockIdx.x * blockDim.x + threadIdx.x;
    int e  = gid >> 5;
    int f4 = gid & 31;
    if (e >= E) return;
    int src, dst;
    load_edge(ei, *flag, E, e, src, dst);
    float w = dinv[src] * dinv[dst];
    float4 v = ((const float4*)xin)[src * 32 + f4];
    if (RELU_IN) v = relu4(v);
    float* o = yout + (size_t)dst * FEAT + f4 * 4;
    atomicAdd(o + 0, v.x * w);
    atomicAdd(o + 1, v.y * w);
    atomicAdd(o + 2, v.z * w);
    atomicAdd(o + 3, v.w * w);
}

__global__ void relu_kernel(float4* buf, int n4) {
    int i = blockIdx.x * blockDim.x + threadIdx.x;
    if (i >= n4) return;
    buf[i] = relu4(buf[i]);
}

extern "C" void kernel_launch(void* const* d_in, const int* in_sizes, int n_in,
                              void* d_out, int out_size, void* d_ws, size_t ws_size,
                              hipStream_t stream) {
    const float* x  = (const float*)d_in[0];
    const void*  ei = d_in[1];
    const int E = in_sizes[1] / 2;

    float* out = (float*)d_out;
    char*  ws  = (char*)d_ws;

    const size_t feat_bytes = (size_t)NN * FEAT * sizeof(float);
    const int NB = (NN + 255) / 256;

    // ws layout (CSR path)
    const size_t OFF_FLAG = 0;
    const size_t OFF_HIST = 1024;
    const size_t OFF_DINV = OFF_HIST + (((size_t)NN * 4 + 255) & ~255ull);
    const size_t OFF_ROWP = OFF_DINV + (((size_t)NN * 4 + 255) & ~255ull);
    const size_t OFF_CURS = OFF_ROWP + ((((size_t)NN + 1) * 4 + 255) & ~255ull);
    const size_t OFF_BSUM = OFF_CURS + (((size_t)NN * 4 + 255) & ~255ull);
    const size_t OFF_EDG  = OFF_BSUM + ((1024 * 4 + 255) & ~255ull);
    const size_t OFF_Y    = OFF_EDG + (((size_t)E * 8 + 255) & ~255ull);
    const size_t NEEDED   = OFF_Y + feat_bytes;

    int* flag = (int*)(ws + OFF_FLAG);

    if (ws_size >= NEEDED) {
        int*   hist = (int*)(ws + OFF_HIST);
        float* dinv = (float*)(ws + OFF_DINV);
        int*   rowp = (int*)(ws + OFF_ROWP);
        int*   curs = (int*)(ws + OFF_CURS);
        int*   bsum = (int*)(ws + OFF_BSUM);
        unsigned long long* edge = (unsigned long long*)(ws + OFF_EDG);
        float* y    = (float*)(ws + OFF_Y);

        hipMemsetAsync(hist, 0, NN * sizeof(int), stream);
        detect_idx_kernel<<<1, 256, 0, stream>>>((const unsigned int*)ei, flag);

        hist_kernel<<<(E + 255) / 256, 256, 0, stream>>>(ei, flag, hist, E);
        scan_local_kernel<<<NB, 256, 0, stream>>>(hist, rowp, bsum, dinv, NN);
        scan_bsum_kernel<<<1, 1024, 0, stream>>>(bsum, NB);
        scan_add_kernel<<<NB, 256, 0, stream>>>(rowp, bsum, rowp, curs, NN, E);
        scatter_kernel<<<(E + 255) / 256, 256, 0, stream>>>(ei, flag, curs, edge, dinv, E);

        const int conv_blocks = (NN * 32 + 255) / 256;
        // layer 1: x -> out
        conv_csr_kernel<false, false><<<conv_blocks, 256, 0, stream>>>(x, rowp, edge, out);
        // layer 2: relu(out) -> y
        conv_csr_kernel<true, false><<<conv_blocks, 256, 0, stream>>>(out, rowp, edge, y);
        // layer 3: relu(y) -> out (+ final relu fused)
        conv_csr_kernel<true, true><<<conv_blocks, 256, 0, stream>>>(y, rowp, edge, out);
    } else {
        // fallback: atomic implementation
        float* dinv = (float*)(ws + 1024);
        float* y    = (float*)(ws + 262144);

        hipMemsetAsync(dinv, 0, NN * sizeof(float), stream);
        hipMemsetAsync(out, 0, feat_bytes, stream);
        hipMemsetAsync(y, 0, feat_bytes, stream);

        detect_idx_kernel<<<1, 256, 0, stream>>>((const unsigned int*)ei, flag);
        deg_kernel<<<(E + 255) / 256, 256, 0, stream>>>(ei, flag, dinv, E);
        dinv_kernel<<<(NN + 255) / 256, 256, 0, stream>>>(dinv);

        const int conv_blocks = (int)(((size_t)E * 32 + 255) / 256);
        conv_atomic_kernel<false><<<conv_blocks, 256, 0, stream>>>(x, ei, flag, dinv, out, E);
        conv_atomic_kernel<true><<<conv_blocks, 256, 0, stream>>>(out, ei, flag, dinv, y, E);
        hipMemsetAsync(out, 0, feat_bytes, stream);
        conv_atomic_kernel<true><<<conv_blocks, 256, 0, stream>>>(y, ei, flag, dinv, out, E);
        relu_kernel<<<(out_size / 4 + 255) / 256, 256, 0, stream>>>((float4*)out, out_size / 4);
    }
}

// Round 7
// 155.218 us; speedup vs baseline: 3.3872x; 1.3298x over previous
//
#include <hip/hip_runtime.h>
#include <hip/hip_fp16.h>

#define NN 50000
#define FEAT 128

// Detect whether edge_index is stored as int64 (high 32-bit words all zero)
__global__ void detect_idx_kernel(const unsigned int* ei32, int* flag) {
    __shared__ int ok;
    if (threadIdx.x == 0) ok = 1;
    __syncthreads();
    if (ei32[2 * threadIdx.x + 1] != 0u) ok = 0;   // benign race: all writers write 0
    __syncthreads();
    if (threadIdx.x == 0) *flag = ok;
}

static __device__ __forceinline__ void load_edge(const void* ei, int is64, int E, int e,
                                                 int& src, int& dst) {
    if (is64) {
        const long long* p = (const long long*)ei;
        src = (int)p[e];
        dst = (int)p[E + e];
    } else {
        const int* p = (const int*)ei;
        src = p[e];
        dst = p[E + e];
    }
}

// ---------------- CSR build ----------------
__global__ void hist_kernel(const void* ei, const int* flag, int* hist, int E) {
    int e = blockIdx.x * blockDim.x + threadIdx.x;
    if (e >= E) return;
    int src, dst;
    load_edge(ei, *flag, E, e, src, dst);
    atomicAdd(&hist[dst], 1);
}

// phase 1: per-block (256) scan -> local excl offsets + block sums + dinv (fused)
__global__ void scan_local_kernel(const int* __restrict__ hist, int* __restrict__ local_excl,
                                  int* __restrict__ bsum, float* __restrict__ dinv, int n) {
    __shared__ int sdata[256];
    int i = blockIdx.x * 256 + threadIdx.x;
    int v = (i < n) ? hist[i] : 0;
    if (i < n) dinv[i] = (v > 0) ? rsqrtf((float)v) : 0.0f;
    sdata[threadIdx.x] = v;
    __syncthreads();
    for (int d = 1; d < 256; d <<= 1) {
        int t = (threadIdx.x >= (unsigned)d) ? sdata[threadIdx.x - d] : 0;
        __syncthreads();
        sdata[threadIdx.x] += t;
        __syncthreads();
    }
    if (i < n) local_excl[i] = sdata[threadIdx.x] - v;
    if (threadIdx.x == 255) bsum[blockIdx.x] = sdata[255];
}

// phase 2: single-block exclusive scan of block sums (nb <= 1024)
__global__ void scan_bsum_kernel(int* bsum, int nb) {
    __shared__ int sdata[1024];
    int v = ((int)threadIdx.x < nb) ? bsum[threadIdx.x] : 0;
    sdata[threadIdx.x] = v;
    __syncthreads();
    for (int d = 1; d < 1024; d <<= 1) {
        int t = (threadIdx.x >= (unsigned)d) ? sdata[threadIdx.x - d] : 0;
        __syncthreads();
        sdata[threadIdx.x] += t;
        __syncthreads();
    }
    if ((int)threadIdx.x < nb) bsum[threadIdx.x] = sdata[threadIdx.x] - v;
}

// phase 3: add block offsets -> row_ptr + cursor; thread 0 writes row_ptr[n]=E
__global__ void scan_add_kernel(const int* __restrict__ local_excl, const int* __restrict__ bsum,
                                int* __restrict__ rowp, int* __restrict__ curs, int n, int E) {
    int i = blockIdx.x * 256 + threadIdx.x;
    if (i < n) {
        int r = local_excl[i] + bsum[i >> 8];
        rowp[i] = r;
        curs[i] = r;
    }
    if (i == 0) rowp[n] = E;
}

// scatter {src, weight} packed into one 8-byte word (low 32 = src, high 32 = w bits)
__global__ void scatter_kernel(const void* ei, const int* flag, int* cursor,
                               unsigned long long* __restrict__ edge,
                               const float* __restrict__ dinv, int E) {
    int e = blockIdx.x * blockDim.x + threadIdx.x;
    if (e >= E) return;
    int src, dst;
    load_edge(ei, *flag, E, e, src, dst);
    int pos = atomicAdd(&cursor[dst], 1);
    float w = dinv[src] * dinv[dst];
    edge[pos] = (unsigned long long)(unsigned int)src |
                ((unsigned long long)(unsigned int)__float_as_int(w) << 32);
}

static __device__ __forceinline__ float4 relu4(float4 v) {
    v.x = fmaxf(v.x, 0.0f); v.y = fmaxf(v.y, 0.0f);
    v.z = fmaxf(v.z, 0.0f); v.w = fmaxf(v.w, 0.0f);
    return v;
}

static __device__ __forceinline__ void fma4(float4& a, float w, float4 v) {
    a.x += w * v.x; a.y += w * v.y; a.z += w * v.z; a.w += w * v.w;
}

static __device__ __forceinline__ float4 h4_to_f4(uint2 r) {
    __half2 lo = *reinterpret_cast<__half2*>(&r.x);
    __half2 hi = *reinterpret_cast<__half2*>(&r.y);
    float2 f0 = __half22float2(lo);
    float2 f1 = __half22float2(hi);
    return make_float4(f0.x, f0.y, f1.x, f1.y);
}

static __device__ __forceinline__ uint2 f4_to_h4(float4 v) {
    __half2 lo = __floats2half2_rn(v.x, v.y);
    __half2 hi = __floats2half2_rn(v.z, v.w);
    uint2 r;
    r.x = *reinterpret_cast<unsigned int*>(&lo);
    r.y = *reinterpret_cast<unsigned int*>(&hi);
    return r;
}

// convert fp32 features -> fp16 rows
__global__ void cvt_f2h_kernel(const float4* __restrict__ in, uint2* __restrict__ outh, int n4) {
    int i = blockIdx.x * blockDim.x + threadIdx.x;
    if (i >= n4) return;
    outh[i] = f4_to_h4(in[i]);
}

// ---------------- CSR conv (fp16 gather, fp32 accum, ReLU fused into store) ----------------
// 32 threads/node, 4 feats/thread (8B fp16). Per 32-edge chunk: ONE coalesced
// packed-edge load, shfl-broadcast, 8-way-ILP clamped gathers.
template <bool OUT_HALF>
__global__ void conv_h_kernel(const uint2* __restrict__ xh,
                              const int* __restrict__ row_ptr,
                              const unsigned long long* __restrict__ edge,
                              void* __restrict__ outbuf) {
    int gid = blockIdx.x * blockDim.x + threadIdx.x;
    int node = gid >> 5;
    int f4   = gid & 31;
    if (node >= NN) return;
    int beg = row_ptr[node];
    int end = row_ptr[node + 1];

    float4 a0 = make_float4(0.f, 0.f, 0.f, 0.f);
    float4 a1 = a0, a2 = a0, a3 = a0;

    for (int cb = beg; cb < end; cb += 32) {
        int rem = end - cb;
        if (rem > 32) rem = 32;
        int myi = (f4 < rem) ? f4 : 0;
        unsigned long long pk = edge[cb + myi];   // one coalesced 8B load / lane

        for (int j = 0; j < rem; j += 8) {
            int i0 = j + 0, i1 = j + 1, i2 = j + 2, i3 = j + 3;
            int i4 = j + 4, i5 = j + 5, i6 = j + 6, i7 = j + 7;
            int last = rem - 1;
            unsigned long long l0 = __shfl(pk, i0 < rem ? i0 : last, 32);
            unsigned long long l1 = __shfl(pk, i1 < rem ? i1 : last, 32);
            unsigned long long l2 = __shfl(pk, i2 < rem ? i2 : last, 32);
            unsigned long long l3 = __shfl(pk, i3 < rem ? i3 : last, 32);
            unsigned long long l4 = __shfl(pk, i4 < rem ? i4 : last, 32);
            unsigned long long l5 = __shfl(pk, i5 < rem ? i5 : last, 32);
            unsigned long long l6 = __shfl(pk, i6 < rem ? i6 : last, 32);
            unsigned long long l7 = __shfl(pk, i7 < rem ? i7 : last, 32);

            float w0 = (i0 < rem) ? __int_as_float((int)(l0 >> 32)) : 0.0f;
            float w1 = (i1 < rem) ? __int_as_float((int)(l1 >> 32)) : 0.0f;
            float w2 = (i2 < rem) ? __int_as_float((int)(l2 >> 32)) : 0.0f;
            float w3 = (i3 < rem) ? __int_as_float((int)(l3 >> 32)) : 0.0f;
            float w4 = (i4 < rem) ? __int_as_float((int)(l4 >> 32)) : 0.0f;
            float w5 = (i5 < rem) ? __int_as_float((int)(l5 >> 32)) : 0.0f;
            float w6 = (i6 < rem) ? __int_as_float((int)(l6 >> 32)) : 0.0f;
            float w7 = (i7 < rem) ? __int_as_float((int)(l7 >> 32)) : 0.0f;

            uint2 r0 = xh[(int)(unsigned int)l0 * 32 + f4];
            uint2 r1 = xh[(int)(unsigned int)l1 * 32 + f4];
            uint2 r2 = xh[(int)(unsigned int)l2 * 32 + f4];
            uint2 r3 = xh[(int)(unsigned int)l3 * 32 + f4];
            uint2 r4 = xh[(int)(unsigned int)l4 * 32 + f4];
            uint2 r5 = xh[(int)(unsigned int)l5 * 32 + f4];
            uint2 r6 = xh[(int)(unsigned int)l6 * 32 + f4];
            uint2 r7 = xh[(int)(unsigned int)l7 * 32 + f4];

            fma4(a0, w0, h4_to_f4(r0));
            fma4(a1, w1, h4_to_f4(r1));
            fma4(a2, w2, h4_to_f4(r2));
            fma4(a3, w3, h4_to_f4(r3));
            fma4(a0, w4, h4_to_f4(r4));
            fma4(a1, w5, h4_to_f4(r5));
            fma4(a2, w6, h4_to_f4(r6));
            fma4(a3, w7, h4_to_f4(r7));
        }
    }

    float4 acc;
    acc.x = (a0.x + a1.x) + (a2.x + a3.x);
    acc.y = (a0.y + a1.y) + (a2.y + a3.y);
    acc.z = (a0.z + a1.z) + (a2.z + a3.z);
    acc.w = (a0.w + a1.w) + (a2.w + a3.w);
    acc = relu4(acc);   // every layer output is ReLU'd

    if (OUT_HALF) {
        ((uint2*)outbuf)[node * 32 + f4] = f4_to_h4(acc);
    } else {
        ((float4*)outbuf)[node * 32 + f4] = acc;
    }
}

// ---------------- fallback (atomic) path kernels ----------------
__global__ void deg_kernel(const void* ei, const int* flag, float* deg, int E) {
    int e = blockIdx.x * blockDim.x + threadIdx.x;
    if (e >= E) return;
    int src, dst;
    load_edge(ei, *flag, E, e, src, dst);
    atomicAdd(&deg[dst], 1.0f);
}

__global__ void dinv_kernel(float* deg) {
    int i = blockIdx.x * blockDim.x + threadIdx.x;
    if (i >= NN) return;
    float d = deg[i];
    deg[i] = (d > 0.0f) ? (1.0f / sqrtf(d)) : 0.0f;
}

template <bool RELU_IN>
__global__ void conv_atomic_kernel(const float* __restrict__ xin, const void* ei, const int* flag,
                                   const float* __restrict__ dinv, float* __restrict__ yout, int E) {
    int gid = blockIdx.x * blockDim.x + threadIdx.x;
    int e  = gid >> 5;
    int f4 = gid & 31;
    if (e >= E) return;
    int src, dst;
    load_edge(ei, *flag, E, e, src, dst);
    float w = dinv[src] * dinv[dst];
    float4 v = ((const float4*)xin)[src * 32 + f4];
    if (RELU_IN) v = relu4(v);
    float* o = yout + (size_t)dst * FEAT + f4 * 4;
    atomicAdd(o + 0, v.x * w);
    atomicAdd(o + 1, v.y * w);
    atomicAdd(o + 2, v.z * w);
    atomicAdd(o + 3, v.w * w);
}

__global__ void relu_kernel(float4* buf, int n4) {
    int i = blockIdx.x * blockDim.x + threadIdx.x;
    if (i >= n4) return;
    buf[i] = relu4(buf[i]);
}

extern "C" void kernel_launch(void* const* d_in, const int* in_sizes, int n_in,
                              void* d_out, int out_size, void* d_ws, size_t ws_size,
                              hipStream_t stream) {
    const float* x  = (const float*)d_in[0];
    const void*  ei = d_in[1];
    const int E = in_sizes[1] / 2;

    float* out = (float*)d_out;
    char*  ws  = (char*)d_ws;

    const size_t feat_bytes  = (size_t)NN * FEAT * sizeof(float);
    const size_t half_bytes  = (size_t)NN * FEAT * sizeof(unsigned short);
    const int NB = (NN + 255) / 256;
    const int N4 = NN * 32;   // float4 / uint2 quads per feature buffer

    // ws layout (CSR fp16 path)
    const size_t OFF_FLAG = 0;
    const size_t OFF_HIST = 1024;
    const size_t OFF_DINV = OFF_HIST + (((size_t)NN * 4 + 255) & ~255ull);
    const size_t OFF_ROWP = OFF_DINV + (((size_t)NN * 4 + 255) & ~255ull);
    const size_t OFF_CURS = OFF_ROWP + ((((size_t)NN + 1) * 4 + 255) & ~255ull);
    const size_t OFF_BSUM = OFF_CURS + (((size_t)NN * 4 + 255) & ~255ull);
    const size_t OFF_EDG  = OFF_BSUM + ((1024 * 4 + 255) & ~255ull);
    const size_t OFF_HA   = OFF_EDG + (((size_t)E * 8 + 255) & ~255ull);
    const size_t OFF_HB   = OFF_HA + ((half_bytes + 255) & ~255ull);
    const size_t NEEDED   = OFF_HB + half_bytes;

    int* flag = (int*)(ws + OFF_FLAG);

    if (ws_size >= NEEDED) {
        int*   hist = (int*)(ws + OFF_HIST);
        float* dinv = (float*)(ws + OFF_DINV);
        int*   rowp = (int*)(ws + OFF_ROWP);
        int*   curs = (int*)(ws + OFF_CURS);
        int*   bsum = (int*)(ws + OFF_BSUM);
        unsigned long long* edge = (unsigned long long*)(ws + OFF_EDG);
        uint2* hA   = (uint2*)(ws + OFF_HA);
        uint2* hB   = (uint2*)(ws + OFF_HB);

        hipMemsetAsync(hist, 0, NN * sizeof(int), stream);
        detect_idx_kernel<<<1, 256, 0, stream>>>((const unsigned int*)ei, flag);

        hist_kernel<<<(E + 255) / 256, 256, 0, stream>>>(ei, flag, hist, E);
        scan_local_kernel<<<NB, 256, 0, stream>>>(hist, rowp, bsum, dinv, NN);
        scan_bsum_kernel<<<1, 1024, 0, stream>>>(bsum, NB);
        scan_add_kernel<<<NB, 256, 0, stream>>>(rowp, bsum, rowp, curs, NN, E);
        scatter_kernel<<<(E + 255) / 256, 256, 0, stream>>>(ei, flag, curs, edge, dinv, E);

        // quantize input features to fp16
        cvt_f2h_kernel<<<(N4 + 255) / 256, 256, 0, stream>>>((const float4*)x, hA, N4);

        const int conv_blocks = (NN * 32 + 255) / 256;
        // layer 1: hA -> hB (relu fused into store)
        conv_h_kernel<true><<<conv_blocks, 256, 0, stream>>>(hA, rowp, edge, hB);
        // layer 2: hB -> hA
        conv_h_kernel<true><<<conv_blocks, 256, 0, stream>>>(hB, rowp, edge, hA);
        // layer 3: hA -> out (fp32)
        conv_h_kernel<false><<<conv_blocks, 256, 0, stream>>>(hA, rowp, edge, out);
    } else {
        // fallback: atomic fp32 implementation
        float* dinv = (float*)(ws + 1024);
        float* y    = (float*)(ws + 262144);

        hipMemsetAsync(dinv, 0, NN * sizeof(float), stream);
        hipMemsetAsync(out, 0, feat_bytes, stream);
        hipMemsetAsync(y, 0, feat_bytes, stream);

        detect_idx_kernel<<<1, 256, 0, stream>>>((const unsigned int*)ei, flag);
        deg_kernel<<<(E + 255) / 256, 256, 0, stream>>>(ei, flag, dinv, E);
        dinv_kernel<<<(NN + 255) / 256, 256, 0, stream>>>(dinv);

        const int conv_blocks = (int)(((size_t)E * 32 + 255) / 256);
        conv_atomic_kernel<false><<<conv_blocks, 256, 0, stream>>>(x, ei, flag, dinv, out, E);
        conv_atomic_kernel<true><<<conv_blocks, 256, 0, stream>>>(out, ei, flag, dinv, y, E);
        hipMemsetAsync(out, 0, feat_bytes, stream);
        conv_atomic_kernel<true><<<conv_blocks, 256, 0, stream>>>(y, ei, flag, dinv, out, E);
        relu_kernel<<<(out_size / 4 + 255) / 256, 256, 0, stream>>>((float4*)out, out_size / 4);
    }
}

// Round 8
// 152.215 us; speedup vs baseline: 3.4540x; 1.0197x over previous
//
#include <hip/hip_runtime.h>
#include <hip/hip_fp16.h>

#define NN 50000
#define FEAT 128

// Zero hist (grid-wide) + detect int64-vs-int32 edge storage (block 0).
__global__ void init_kernel(const unsigned int* ei32, int* flag, int* hist, int n) {
    int i = blockIdx.x * 256 + threadIdx.x;
    if (i < n) hist[i] = 0;
    if (blockIdx.x == 0) {
        __shared__ int ok;
        if (threadIdx.x == 0) ok = 1;
        __syncthreads();
        if (ei32[2 * threadIdx.x + 1] != 0u) ok = 0;   // benign race: all writers write 0
        __syncthreads();
        if (threadIdx.x == 0) *flag = ok;
    }
}

static __device__ __forceinline__ void load_edge(const void* ei, int is64, int E, int e,
                                                 int& src, int& dst) {
    if (is64) {
        const long long* p = (const long long*)ei;
        src = (int)p[e];
        dst = (int)p[E + e];
    } else {
        const int* p = (const int*)ei;
        src = p[e];
        dst = p[E + e];
    }
}

// ---------------- CSR build ----------------
__global__ void hist_kernel(const void* ei, const int* flag, int* hist, int E) {
    int e = blockIdx.x * blockDim.x + threadIdx.x;
    if (e >= E) return;
    int src, dst;
    load_edge(ei, *flag, E, e, src, dst);
    atomicAdd(&hist[dst], 1);
}

// phase 1: per-block (256) scan -> local excl offsets + block sums + dinv (fused)
__global__ void scan_local_kernel(const int* __restrict__ hist, int* __restrict__ local_excl,
                                  int* __restrict__ bsum, float* __restrict__ dinv, int n) {
    __shared__ int sdata[256];
    int i = blockIdx.x * 256 + threadIdx.x;
    int v = (i < n) ? hist[i] : 0;
    if (i < n) dinv[i] = (v > 0) ? rsqrtf((float)v) : 0.0f;
    sdata[threadIdx.x] = v;
    __syncthreads();
    for (int d = 1; d < 256; d <<= 1) {
        int t = (threadIdx.x >= (unsigned)d) ? sdata[threadIdx.x - d] : 0;
        __syncthreads();
        sdata[threadIdx.x] += t;
        __syncthreads();
    }
    if (i < n) local_excl[i] = sdata[threadIdx.x] - v;
    if (threadIdx.x == 255) bsum[blockIdx.x] = sdata[255];
}

// phase 2: single-block exclusive scan of block sums (nb <= 1024)
__global__ void scan_bsum_kernel(int* bsum, int nb) {
    __shared__ int sdata[1024];
    int v = ((int)threadIdx.x < nb) ? bsum[threadIdx.x] : 0;
    sdata[threadIdx.x] = v;
    __syncthreads();
    for (int d = 1; d < 1024; d <<= 1) {
        int t = (threadIdx.x >= (unsigned)d) ? sdata[threadIdx.x - d] : 0;
        __syncthreads();
        sdata[threadIdx.x] += t;
        __syncthreads();
    }
    if ((int)threadIdx.x < nb) bsum[threadIdx.x] = sdata[threadIdx.x] - v;
}

// phase 3: add block offsets -> row_ptr + cursor; thread 0 writes row_ptr[n]=E
__global__ void scan_add_kernel(const int* __restrict__ local_excl, const int* __restrict__ bsum,
                                int* __restrict__ rowp, int* __restrict__ curs, int n, int E) {
    int i = blockIdx.x * 256 + threadIdx.x;
    if (i < n) {
        int r = local_excl[i] + bsum[i >> 8];
        rowp[i] = r;
        curs[i] = r;
    }
    if (i == 0) rowp[n] = E;
}

// scatter {src, weight} packed into one 8-byte word (low 32 = src, high 32 = w bits)
__global__ void scatter_kernel(const void* ei, const int* flag, int* cursor,
                               unsigned long long* __restrict__ edge,
                               const float* __restrict__ dinv, int E) {
    int e = blockIdx.x * blockDim.x + threadIdx.x;
    if (e >= E) return;
    int src, dst;
    load_edge(ei, *flag, E, e, src, dst);
    int pos = atomicAdd(&cursor[dst], 1);
    float w = dinv[src] * dinv[dst];
    edge[pos] = (unsigned long long)(unsigned int)src |
                ((unsigned long long)(unsigned int)__float_as_int(w) << 32);
}

static __device__ __forceinline__ float4 relu4(float4 v) {
    v.x = fmaxf(v.x, 0.0f); v.y = fmaxf(v.y, 0.0f);
    v.z = fmaxf(v.z, 0.0f); v.w = fmaxf(v.w, 0.0f);
    return v;
}

static __device__ __forceinline__ void fma4(float4& a, float w, float4 v) {
    a.x += w * v.x; a.y += w * v.y; a.z += w * v.z; a.w += w * v.w;
}

static __device__ __forceinline__ float4 h4_to_f4(uint2 r) {
    __half2 lo = *reinterpret_cast<__half2*>(&r.x);
    __half2 hi = *reinterpret_cast<__half2*>(&r.y);
    float2 f0 = __half22float2(lo);
    float2 f1 = __half22float2(hi);
    return make_float4(f0.x, f0.y, f1.x, f1.y);
}

static __device__ __forceinline__ uint2 f4_to_h4(float4 v) {
    __half2 lo = __floats2half2_rn(v.x, v.y);
    __half2 hi = __floats2half2_rn(v.z, v.w);
    uint2 r;
    r.x = *reinterpret_cast<unsigned int*>(&lo);
    r.y = *reinterpret_cast<unsigned int*>(&hi);
    return r;
}

// convert fp32 features -> fp16 rows
__global__ void cvt_f2h_kernel(const float4* __restrict__ in, uint2* __restrict__ outh, int n4) {
    int i = blockIdx.x * blockDim.x + threadIdx.x;
    if (i >= n4) return;
    outh[i] = f4_to_h4(in[i]);
}

// ---------------- CSR conv (fp16 gather, fp32 accum, ReLU fused into store) ----------------
template <bool OUT_HALF>
__global__ void conv_h_kernel(const uint2* __restrict__ xh,
                              const int* __restrict__ row_ptr,
                              const unsigned long long* __restrict__ edge,
                              void* __restrict__ outbuf) {
    int gid = blockIdx.x * blockDim.x + threadIdx.x;
    int node = gid >> 5;
    int f4   = gid & 31;
    if (node >= NN) return;
    int beg = row_ptr[node];
    int end = row_ptr[node + 1];

    float4 a0 = make_float4(0.f, 0.f, 0.f, 0.f);
    float4 a1 = a0, a2 = a0, a3 = a0;

    for (int cb = beg; cb < end; cb += 32) {
        int rem = end - cb;
        if (rem > 32) rem = 32;
        int myi = (f4 < rem) ? f4 : 0;
        unsigned long long pk = edge[cb + myi];   // one coalesced 8B load / lane

        for (int j = 0; j < rem; j += 8) {
            int i0 = j + 0, i1 = j + 1, i2 = j + 2, i3 = j + 3;
            int i4 = j + 4, i5 = j + 5, i6 = j + 6, i7 = j + 7;
            int last = rem - 1;
            unsigned long long l0 = __shfl(pk, i0 < rem ? i0 : last, 32);
            unsigned long long l1 = __shfl(pk, i1 < rem ? i1 : last, 32);
            unsigned long long l2 = __shfl(pk, i2 < rem ? i2 : last, 32);
            unsigned long long l3 = __shfl(pk, i3 < rem ? i3 : last, 32);
            unsigned long long l4 = __shfl(pk, i4 < rem ? i4 : last, 32);
            unsigned long long l5 = __shfl(pk, i5 < rem ? i5 : last, 32);
            unsigned long long l6 = __shfl(pk, i6 < rem ? i6 : last, 32);
            unsigned long long l7 = __shfl(pk, i7 < rem ? i7 : last, 32);

            float w0 = (i0 < rem) ? __int_as_float((int)(l0 >> 32)) : 0.0f;
            float w1 = (i1 < rem) ? __int_as_float((int)(l1 >> 32)) : 0.0f;
            float w2 = (i2 < rem) ? __int_as_float((int)(l2 >> 32)) : 0.0f;
            float w3 = (i3 < rem) ? __int_as_float((int)(l3 >> 32)) : 0.0f;
            float w4 = (i4 < rem) ? __int_as_float((int)(l4 >> 32)) : 0.0f;
            float w5 = (i5 < rem) ? __int_as_float((int)(l5 >> 32)) : 0.0f;
            float w6 = (i6 < rem) ? __int_as_float((int)(l6 >> 32)) : 0.0f;
            float w7 = (i7 < rem) ? __int_as_float((int)(l7 >> 32)) : 0.0f;

            uint2 r0 = xh[(int)(unsigned int)l0 * 32 + f4];
            uint2 r1 = xh[(int)(unsigned int)l1 * 32 + f4];
            uint2 r2 = xh[(int)(unsigned int)l2 * 32 + f4];
            uint2 r3 = xh[(int)(unsigned int)l3 * 32 + f4];
            uint2 r4 = xh[(int)(unsigned int)l4 * 32 + f4];
            uint2 r5 = xh[(int)(unsigned int)l5 * 32 + f4];
            uint2 r6 = xh[(int)(unsigned int)l6 * 32 + f4];
            uint2 r7 = xh[(int)(unsigned int)l7 * 32 + f4];

            fma4(a0, w0, h4_to_f4(r0));
            fma4(a1, w1, h4_to_f4(r1));
            fma4(a2, w2, h4_to_f4(r2));
            fma4(a3, w3, h4_to_f4(r3));
            fma4(a0, w4, h4_to_f4(r4));
            fma4(a1, w5, h4_to_f4(r5));
            fma4(a2, w6, h4_to_f4(r6));
            fma4(a3, w7, h4_to_f4(r7));
        }
    }

    float4 acc;
    acc.x = (a0.x + a1.x) + (a2.x + a3.x);
    acc.y = (a0.y + a1.y) + (a2.y + a3.y);
    acc.z = (a0.z + a1.z) + (a2.z + a3.z);
    acc.w = (a0.w + a1.w) + (a2.w + a3.w);
    acc = relu4(acc);   // every layer output is ReLU'd

    if (OUT_HALF) {
        ((uint2*)outbuf)[node * 32 + f4] = f4_to_h4(acc);
    } else {
        ((float4*)outbuf)[node * 32 + f4] = acc;
    }
}

// ---------------- fallback (atomic) path kernels ----------------
__global__ void deg_kernel(const void* ei, const int* flag, float* deg, int E) {
    int e = blockIdx.x * blockDim.x + threadIdx.x;
    if (e >= E) return;
    int src, dst;
    load_edge(ei, *flag, E, e, src, dst);
    atomicAdd(&deg[dst], 1.0f);
}

__global__ void dinv_kernel(float* deg) {
    int i = blockIdx.x * blockDim.x + threadIdx.x;
    if (i >= NN) return;
    float d = deg[i];
    deg[i] = (d > 0.0f) ? (1.0f / sqrtf(d)) : 0.0f;
}

template <bool RELU_IN>
__global__ void conv_atomic_kernel(const float* __restrict__ xin, const void* ei, const int* flag,
                                   const float* __restrict__ dinv, float* __restrict__ yout, int E) {
    int gid = blockIdx.x * blockDim.x + threadIdx.x;
    int e  = gid >> 5;
    int f4 = gid & 31;
    if (e >= E) return;
    int src, dst;
    load_edge(ei, *flag, E, e, src, dst);
    float w = dinv[src] * dinv[dst];
    float4 v = ((const float4*)xin)[src * 32 + f4];
    if (RELU_IN) v = relu4(v);
    float* o = yout + (size_t)dst * FEAT + f4 * 4;
    atomicAdd(o + 0, v.x * w);
    atomicAdd(o + 1, v.y * w);
    atomicAdd(o + 2, v.z * w);
    atomicAdd(o + 3, v.w * w);
}

__global__ void relu_kernel(float4* buf, int n4) {
    int i = blockIdx.x * blockDim.x + threadIdx.x;
    if (i >= n4) return;
    buf[i] = relu4(buf[i]);
}

extern "C" void kernel_launch(void* const* d_in, const int* in_sizes, int n_in,
                              void* d_out, int out_size, void* d_ws, size_t ws_size,
                              hipStream_t stream) {
    const float* x  = (const float*)d_in[0];
    const void*  ei = d_in[1];
    const int E = in_sizes[1] / 2;

    float* out = (float*)d_out;
    char*  ws  = (char*)d_ws;

    const size_t feat_bytes  = (size_t)NN * FEAT * sizeof(float);
    const size_t half_bytes  = (size_t)NN * FEAT * sizeof(unsigned short);
    const int NB = (NN + 255) / 256;
    const int N4 = NN * 32;

    // ws layout (CSR fp16 path)
    const size_t OFF_FLAG = 0;
    const size_t OFF_HIST = 1024;
    const size_t OFF_DINV = OFF_HIST + (((size_t)NN * 4 + 255) & ~255ull);
    const size_t OFF_ROWP = OFF_DINV + (((size_t)NN * 4 + 255) & ~255ull);
    const size_t OFF_CURS = OFF_ROWP + ((((size_t)NN + 1) * 4 + 255) & ~255ull);
    const size_t OFF_BSUM = OFF_CURS + (((size_t)NN * 4 + 255) & ~255ull);
    const size_t OFF_EDG  = OFF_BSUM + ((1024 * 4 + 255) & ~255ull);
    const size_t OFF_HA   = OFF_EDG + (((size_t)E * 8 + 255) & ~255ull);
    const size_t OFF_HB   = OFF_HA + ((half_bytes + 255) & ~255ull);
    const size_t NEEDED   = OFF_HB + half_bytes;

    int* flag = (int*)(ws + OFF_FLAG);

    if (ws_size >= NEEDED) {
        int*   hist = (int*)(ws + OFF_HIST);
        float* dinv = (float*)(ws + OFF_DINV);
        int*   rowp = (int*)(ws + OFF_ROWP);
        int*   curs = (int*)(ws + OFF_CURS);
        int*   bsum = (int*)(ws + OFF_BSUM);
        unsigned long long* edge = (unsigned long long*)(ws + OFF_EDG);
        uint2* hA   = (uint2*)(ws + OFF_HA);
        uint2* hB   = (uint2*)(ws + OFF_HB);

        // zero hist + detect idx width in ONE kernel (no hipMemsetAsync in the graph)
        init_kernel<<<NB, 256, 0, stream>>>((const unsigned int*)ei, flag, hist, NN);

        hist_kernel<<<(E + 255) / 256, 256, 0, stream>>>(ei, flag, hist, E);
        scan_local_kernel<<<NB, 256, 0, stream>>>(hist, rowp, bsum, dinv, NN);
        scan_bsum_kernel<<<1, 1024, 0, stream>>>(bsum, NB);
        scan_add_kernel<<<NB, 256, 0, stream>>>(rowp, bsum, rowp, curs, NN, E);
        scatter_kernel<<<(E + 255) / 256, 256, 0, stream>>>(ei, flag, curs, edge, dinv, E);

        // quantize input features to fp16
        cvt_f2h_kernel<<<(N4 + 255) / 256, 256, 0, stream>>>((const float4*)x, hA, N4);

        const int conv_blocks = (NN * 32 + 255) / 256;
        conv_h_kernel<true><<<conv_blocks, 256, 0, stream>>>(hA, rowp, edge, hB);
        conv_h_kernel<true><<<conv_blocks, 256, 0, stream>>>(hB, rowp, edge, hA);
        conv_h_kernel<false><<<conv_blocks, 256, 0, stream>>>(hA, rowp, edge, out);
    } else {
        // fallback: atomic fp32 implementation
        float* dinv = (float*)(ws + 1024);
        float* y    = (float*)(ws + 262144);

        hipMemsetAsync(dinv, 0, NN * sizeof(float), stream);
        hipMemsetAsync(out, 0, feat_bytes, stream);
        hipMemsetAsync(y, 0, feat_bytes, stream);

        init_kernel<<<1, 256, 0, stream>>>((const unsigned int*)ei, flag, (int*)(ws + 512), 256);
        deg_kernel<<<(E + 255) / 256, 256, 0, stream>>>(ei, flag, dinv, E);
        dinv_kernel<<<(NN + 255) / 256, 256, 0, stream>>>(dinv);

        const int conv_blocks = (int)(((size_t)E * 32 + 255) / 256);
        conv_atomic_kernel<false><<<conv_blocks, 256, 0, stream>>>(x, ei, flag, dinv, out, E);
        conv_atomic_kernel<true><<<conv_blocks, 256, 0, stream>>>(out, ei, flag, dinv, y, E);
        hipMemsetAsync(out, 0, feat_bytes, stream);
        conv_atomic_kernel<true><<<conv_blocks, 256, 0, stream>>>(y, ei, flag, dinv, out, E);
        relu_kernel<<<(out_size / 4 + 255) / 256, 256, 0, stream>>>((float4*)out, out_size / 4);
    }
}